// Round 5
// baseline (505.230 us; speedup 1.0000x reference)
//
#include <hip/hip_runtime.h>
#include <math.h>

#define T_TOKENS 8192
#define HID      4096
#define NEXP     512
#define TOPK     12
#define RSCALE   2.5f

// ---------------- shared helpers (verified round 1) ----------------

__device__ __forceinline__ unsigned int fkey(float f) {
    unsigned int u = __float_as_uint(f);
    return (u & 0x80000000u) ? ~u : (u | 0x80000000u);  // monotonic float->uint
}

__device__ __forceinline__ float pick8(const float* p, int j) {
    float v = p[0];
    if (j == 1) v = p[1];
    if (j == 2) v = p[2];
    if (j == 3) v = p[3];
    if (j == 4) v = p[4];
    if (j == 5) v = p[5];
    if (j == 6) v = p[6];
    if (j == 7) v = p[7];
    return v;
}

// ================== fp16x3 split-precision common (verified rounds 3/4) ==================
// x = xh + 2^-12 xl + O(2^-22 x)   (RNE hi, RNE scaled residual)
// logits*64 = accH(xh*wh) + 2^-12 * accC(xh*wl + xl*wh), W pre-scaled *64.

typedef __attribute__((ext_vector_type(8))) _Float16 f16x8;
typedef __attribute__((ext_vector_type(4))) float    f32x4;

// float4 -> 4 packed hi halves (uint2) + 4 packed scaled-lo halves (uint2), RNE
__device__ __forceinline__ void cvt4(const float4 f, uint2& h, uint2& l) {
    _Float16 h0 = (_Float16)f.x, h1 = (_Float16)f.y;
    _Float16 h2 = (_Float16)f.z, h3 = (_Float16)f.w;
    float r0 = (f.x - (float)h0) * 4096.f;
    float r1 = (f.y - (float)h1) * 4096.f;
    float r2 = (f.z - (float)h2) * 4096.f;
    float r3 = (f.w - (float)h3) * 4096.f;
    _Float16 l0 = (_Float16)r0, l1 = (_Float16)r1;
    _Float16 l2 = (_Float16)r2, l3 = (_Float16)r3;
    union P { _Float16 q[2]; unsigned int u; } p;
    p.q[0] = h0; p.q[1] = h1; h.x = p.u;
    p.q[0] = h2; p.q[1] = h3; h.y = p.u;
    p.q[0] = l0; p.q[1] = l1; l.x = p.u;
    p.q[0] = l2; p.q[1] = l3; l.y = p.u;
}

// floats [a|b] (k-order 0..7) -> f16x8 hi / f16x8 lo, bit-identical to rounds 3/4 LDS planes
__device__ __forceinline__ void cvt8(const float4 a, const float4 b, f16x8& hi, f16x8& lo) {
    union U { f16x8 v; uint2 u[2]; } H, L;
    uint2 h0, l0, h1, l1;
    cvt4(a, h0, l0);
    cvt4(b, h1, l1);
    H.u[0] = h0; H.u[1] = h1;
    L.u[0] = l0; L.u[1] = l1;
    hi = H.v; lo = L.v;
}

__device__ __forceinline__ void load_lds16(const void* g, void* l) {
    __builtin_amdgcn_global_load_lds((const __attribute__((address_space(1))) void*)g,
                                     (__attribute__((address_space(3))) void*)l,
                                     16, 0, 0);
}

// ================== Kernel 0: W -> fp16 planes, DMA-ready swizzled layout ==================
// (verified round 4) Wp slot (kc, e, p) 16 B at ((kc*512+e)*8+p)*16 holds group g = p ^ (e&7):
//   g<4: hi fp16 of 64*W[e][kc*32+g*8 .. +7];  g>=4: lo plane of same k-range.

__global__ void wconv_kernel(const float* __restrict__ W, uint4* __restrict__ Wp) {
    const int gid = blockIdx.x * 256 + threadIdx.x;   // 524288 total
    const int e  = gid >> 10;
    const int kc = (gid >> 3) & 127;
    const int p  = gid & 7;
    const int g  = p ^ (e & 7);
    const int kbase = kc * 32 + (g & 3) * 8;
    const float* src = W + (size_t)e * HID + kbase;
    const float4 f0 = *(const float4*)src;
    const float4 f1 = *(const float4*)(src + 4);
    const float v[8] = {f0.x, f0.y, f0.z, f0.w, f1.x, f1.y, f1.z, f1.w};

    union H { _Float16 f; unsigned short u; } cv;
    unsigned short h[8];
    if (g < 4) {
        #pragma unroll
        for (int j = 0; j < 8; j++) { cv.f = (_Float16)(v[j] * 64.f); h[j] = cv.u; }
    } else {
        #pragma unroll
        for (int j = 0; j < 8; j++) {
            const float w64 = v[j] * 64.f;
            const _Float16 hh = (_Float16)w64;
            cv.f = (_Float16)((w64 - (float)hh) * 4096.f);
            h[j] = cv.u;
        }
    }
    union O { unsigned short q[8]; uint4 u; } o;
    #pragma unroll
    for (int j = 0; j < 8; j++) o.q[j] = h[j];
    Wp[(size_t)(kc * 512 + e) * 8 + p] = o.u;
}

// ================== Kernel 1: fused GEMM + softmax + top-12 ==================
// Block: 32 tokens x ALL 512 experts. 8 waves; wave w owns 32 tokens x experts [w*64, w*64+64).
// W planes DMA'd (pre-swizzled); A fragments straight from global (L1-resident 4 KB tile).
// Epilogue: logits -> LDS (reusing W buffer), then round-1-verified softmax/top-12,
// 4 tokens per wave. Per-element accumulation order identical to rounds 3/4.

__launch_bounds__(512, 2)
__global__ void fused_kernel(const float* __restrict__ X,
                             const uint4* __restrict__ Wp,
                             const float* __restrict__ bias,
                             float* __restrict__ out)
{
    __shared__ __align__(16) unsigned char S[65536];   // W planes; reused as logits[32][512]

    const int tid  = threadIdx.x;
    const int lane = tid & 63;
    const int w    = tid >> 6;           // 0..7
    const int tok0 = blockIdx.x * 32;

    const int m16   = lane & 15;
    const int q     = lane >> 4;
    const int waveN = w * 64;

    // W DMA: per-lane global src, wave-uniform LDS dst (wave w covers experts w*64..+63)
    const char* wsrc = (const char*)Wp + (size_t)w * 8192 + lane * 16;
    unsigned char* wdst = S + w * 8192;

    // A rows for this lane: tokens m16 and 16+m16; k chunk q*8 within each 32-k tile
    const float* xr0 = X + (size_t)(tok0 + m16) * HID + q * 8;
    const float* xr1 = X + (size_t)(tok0 + 16 + m16) * HID + q * 8;

    // prefetch kc=0
    float4 a00 = *(const float4*)(xr0);
    float4 a01 = *(const float4*)(xr0 + 4);
    float4 a10 = *(const float4*)(xr1);
    float4 a11 = *(const float4*)(xr1 + 4);

    f32x4 accH[2][4], accC[2][4];
    #pragma unroll
    for (int mi = 0; mi < 2; mi++)
        #pragma unroll
        for (int ni = 0; ni < 4; ni++) { accH[mi][ni] = (f32x4)0.f; accC[mi][ni] = (f32x4)0.f; }

    #pragma unroll 1
    for (int kc = 0; kc < HID / 32; kc++) {
        __syncthreads();   // all waves done reading S from previous iteration

        // async W planes -> LDS (64 KB per iter, pre-swizzled; src/dst both lane-ordered)
        #pragma unroll
        for (int s = 0; s < 8; s++)
            load_lds16(wsrc + (size_t)kc * 65536 + s * 1024, wdst + s * 1024);

        // convert current A regs -> fp16 hi/lo fragments (overlaps DMA)
        f16x8 Ah[2], Al[2];
        cvt8(a00, a01, Ah[0], Al[0]);
        cvt8(a10, a11, Ah[1], Al[1]);

        __syncthreads();   // drains vmcnt: W DMA complete

        // prefetch next A tile (overlaps MFMA phase)
        if (kc + 1 < HID / 32) {
            const int off = (kc + 1) * 32;
            a00 = *(const float4*)(xr0 + off);
            a01 = *(const float4*)(xr0 + off + 4);
            a10 = *(const float4*)(xr1 + off);
            a11 = *(const float4*)(xr1 + off + 4);
        }

        // B fragments from swizzled LDS rows (verified round 4): row slot t holds group t^(row&7)
        f16x8 Bh[4], Bl[4];
        #pragma unroll
        for (int ni = 0; ni < 4; ni++) {
            const int row = waveN + ni * 16 + m16;
            const unsigned char* pr = S + row * 128;
            const int r7 = row & 7;
            Bh[ni] = *(const f16x8*)(pr + ((q ^ r7) << 4));
            Bl[ni] = *(const f16x8*)(pr + (((4 | q) ^ r7) << 4));
        }

        #pragma unroll
        for (int mi = 0; mi < 2; mi++)
            #pragma unroll
            for (int ni = 0; ni < 4; ni++) {
                accH[mi][ni] = __builtin_amdgcn_mfma_f32_16x16x32_f16(Ah[mi], Bh[ni], accH[mi][ni], 0, 0, 0);
                accC[mi][ni] = __builtin_amdgcn_mfma_f32_16x16x32_f16(Ah[mi], Bl[ni], accC[mi][ni], 0, 0, 0);
                accC[mi][ni] = __builtin_amdgcn_mfma_f32_16x16x32_f16(Al[mi], Bh[ni], accC[mi][ni], 0, 0, 0);
            }
    }

    __syncthreads();   // all waves done with W LDS -> safe to overwrite with logits

    // logits -> LDS. C/D layout (verified m89/m91): col = lane&15, row = q*4 + reg
    float* Lg = (float*)S;   // [32][512]
    #pragma unroll
    for (int mi = 0; mi < 2; mi++)
        #pragma unroll
        for (int ni = 0; ni < 4; ni++) {
            const int e = waveN + ni * 16 + m16;
            #pragma unroll
            for (int r = 0; r < 4; r++) {
                const int tl = mi * 16 + q * 4 + r;   // token local 0..31
                Lg[tl * NEXP + e] =
                    (accH[mi][ni][r] + accC[mi][ni][r] * (1.f / 4096.f)) * (1.f / 64.f);
            }
        }
    __syncthreads();

    // ---- softmax + biased top-12 (round-1 verified math), 4 tokens per wave ----
    const float4 bs0 = *(const float4*)&bias[4 * lane];
    const float4 bs1 = *(const float4*)&bias[256 + 4 * lane];
    const float br[8] = {bs0.x, bs0.y, bs0.z, bs0.w, bs1.x, bs1.y, bs1.z, bs1.w};

    for (int t = 0; t < 4; t++) {
        const int tl  = w * 4 + t;
        const int tok = tok0 + tl;

        const float4 z0 = *(const float4*)&Lg[tl * NEXP + 4 * lane];
        const float4 z1 = *(const float4*)&Lg[tl * NEXP + 256 + 4 * lane];
        float z[8] = {z0.x, z0.y, z0.z, z0.w, z1.x, z1.y, z1.z, z1.w};

        float m = z[0];
        #pragma unroll
        for (int j = 1; j < 8; j++) m = fmaxf(m, z[j]);
        #pragma unroll
        for (int off = 32; off >= 1; off >>= 1) m = fmaxf(m, __shfl_xor(m, off));

        float p[8];
        float s = 0.f;
        #pragma unroll
        for (int j = 0; j < 8; j++) { p[j] = expf(z[j] - m); s += p[j]; }
        #pragma unroll
        for (int off = 32; off >= 1; off >>= 1) s += __shfl_xor(s, off);
        const float inv = 1.f / s;

        float pb[8], bb[8];
        #pragma unroll
        for (int j = 0; j < 8; j++) {
            pb[j] = p[j] * inv;
            bb[j] = pb[j] + br[j];
        }

        for (int kk = 0; kk < TOPK; kk++) {
            unsigned long long key = 0ull;
            #pragma unroll
            for (int j = 0; j < 8; j++) {
                int e = (j < 4) ? (4 * lane + j) : (256 + 4 * lane + (j - 4));
                unsigned long long k64 =
                    ((unsigned long long)fkey(bb[j]) << 32) |
                    (unsigned long long)(unsigned int)(1023 - e);
                key = (k64 > key) ? k64 : key;
            }
            #pragma unroll
            for (int off = 32; off >= 1; off >>= 1) {
                unsigned long long o = __shfl_xor(key, off);
                key = (o > key) ? o : key;
            }
            const int estar = 1023 - (int)(unsigned int)(key & 0xffffffffull);

            int lstar, jstar;
            if (estar < 256) { lstar = estar >> 2;         jstar = estar & 3; }
            else             { lstar = (estar - 256) >> 2; jstar = 4 + ((estar - 256) & 3); }

            const float pj   = pick8(pb, jstar);
            const float psel = __shfl(pj, lstar);

            if (lane == lstar) {
                if (jstar == 0) bb[0] = -INFINITY;
                if (jstar == 1) bb[1] = -INFINITY;
                if (jstar == 2) bb[2] = -INFINITY;
                if (jstar == 3) bb[3] = -INFINITY;
                if (jstar == 4) bb[4] = -INFINITY;
                if (jstar == 5) bb[5] = -INFINITY;
                if (jstar == 6) bb[6] = -INFINITY;
                if (jstar == 7) bb[7] = -INFINITY;
            }

            if (lane == 0) {
                out[(size_t)tok * TOPK + kk] = psel * RSCALE;
                out[(size_t)T_TOKENS * TOPK + (size_t)tok * TOPK + kk] = (float)estar;
            }
        }
    }
}

// ================== Fallback: round-1 fused fp32 kernel (verified) ==================

#define TM   32
#define BK   16
#define EPAD (NEXP + 4)
#define XPAD 36

__launch_bounds__(256, 1)
__global__ void router_kernel(const float* __restrict__ X,
                              const float* __restrict__ W,
                              const float* __restrict__ bias,
                              float* __restrict__ out)
{
    __shared__ float Wsh[BK][EPAD];
    __shared__ float Xsh[BK][XPAD];

    const int tid  = threadIdx.x;
    const int lane = tid & 63;
    const int wave = tid >> 6;
    const int tok0 = blockIdx.x * TM;

    float acc[8][8];
    #pragma unroll
    for (int i = 0; i < 8; i++)
        #pragma unroll
        for (int j = 0; j < 8; j++) acc[i][j] = 0.f;

    const int xt = tid >> 4;
    const int xk = tid & 15;

    for (int k0 = 0; k0 < HID; k0 += BK) {
        #pragma unroll
        for (int r = 0; r < 2; r++) {
            int t = r * 16 + xt;
            Xsh[xk][t] = X[(size_t)(tok0 + t) * HID + k0 + xk];
        }
        #pragma unroll
        for (int r = 0; r < 8; r++) {
            int flat4 = r * 256 + tid;
            int e  = flat4 >> 2;
            int kq = (flat4 & 3) * 4;
            const float4 wv = *(const float4*)&W[(size_t)e * HID + k0 + kq];
            Wsh[kq + 0][e] = wv.x;
            Wsh[kq + 1][e] = wv.y;
            Wsh[kq + 2][e] = wv.z;
            Wsh[kq + 3][e] = wv.w;
        }
        __syncthreads();

        #pragma unroll
        for (int k = 0; k < BK; k++) {
            float4 b0 = *(const float4*)&Wsh[k][4 * lane];
            float4 b1 = *(const float4*)&Wsh[k][256 + 4 * lane];
            float4 a0 = *(const float4*)&Xsh[k][wave * 8];
            float4 a1 = *(const float4*)&Xsh[k][wave * 8 + 4];
            float a[8] = {a0.x, a0.y, a0.z, a0.w, a1.x, a1.y, a1.z, a1.w};
            float b[8] = {b0.x, b0.y, b0.z, b0.w, b1.x, b1.y, b1.z, b1.w};
            #pragma unroll
            for (int i = 0; i < 8; i++)
                #pragma unroll
                for (int j = 0; j < 8; j++)
                    acc[i][j] = fmaf(a[i], b[j], acc[i][j]);
        }
        __syncthreads();
    }

    const float4 bs0 = *(const float4*)&bias[4 * lane];
    const float4 bs1 = *(const float4*)&bias[256 + 4 * lane];
    const float br[8] = {bs0.x, bs0.y, bs0.z, bs0.w, bs1.x, bs1.y, bs1.z, bs1.w};

    for (int i = 0; i < 8; i++) {
        const int tok = tok0 + wave * 8 + i;

        float m = acc[i][0];
        #pragma unroll
        for (int j = 1; j < 8; j++) m = fmaxf(m, acc[i][j]);
        #pragma unroll
        for (int off = 32; off >= 1; off >>= 1) m = fmaxf(m, __shfl_xor(m, off));

        float p[8];
        float s = 0.f;
        #pragma unroll
        for (int j = 0; j < 8; j++) { p[j] = expf(acc[i][j] - m); s += p[j]; }
        #pragma unroll
        for (int off = 32; off >= 1; off >>= 1) s += __shfl_xor(s, off);
        const float inv = 1.f / s;

        float pb[8], bb[8];
        #pragma unroll
        for (int j = 0; j < 8; j++) {
            pb[j] = p[j] * inv;
            bb[j] = pb[j] + br[j];
        }

        for (int kk = 0; kk < TOPK; kk++) {
            unsigned long long key = 0ull;
            #pragma unroll
            for (int j = 0; j < 8; j++) {
                int e = (j < 4) ? (4 * lane + j) : (256 + 4 * lane + (j - 4));
                unsigned long long k64 =
                    ((unsigned long long)fkey(bb[j]) << 32) |
                    (unsigned long long)(unsigned int)(1023 - e);
                key = (k64 > key) ? k64 : key;
            }
            #pragma unroll
            for (int off = 32; off >= 1; off >>= 1) {
                unsigned long long o = __shfl_xor(key, off);
                key = (o > key) ? o : key;
            }
            const int estar = 1023 - (int)(unsigned int)(key & 0xffffffffull);

            int lstar, jstar;
            if (estar < 256) { lstar = estar >> 2;         jstar = estar & 3; }
            else             { lstar = (estar - 256) >> 2; jstar = 4 + ((estar - 256) & 3); }

            const float pj   = pick8(pb, jstar);
            const float psel = __shfl(pj, lstar);

            if (lane == lstar) {
                if (jstar == 0) bb[0] = -INFINITY;
                if (jstar == 1) bb[1] = -INFINITY;
                if (jstar == 2) bb[2] = -INFINITY;
                if (jstar == 3) bb[3] = -INFINITY;
                if (jstar == 4) bb[4] = -INFINITY;
                if (jstar == 5) bb[5] = -INFINITY;
                if (jstar == 6) bb[6] = -INFINITY;
                if (jstar == 7) bb[7] = -INFINITY;
            }

            if (lane == 0) {
                out[(size_t)tok * TOPK + kk] = psel * RSCALE;
                out[(size_t)T_TOKENS * TOPK + (size_t)tok * TOPK + kk] = (float)estar;
            }
        }
    }
}

// ================== launcher ==================

extern "C" void kernel_launch(void* const* d_in, const int* in_sizes, int n_in,
                              void* d_out, int out_size, void* d_ws, size_t ws_size,
                              hipStream_t stream)
{
    const float* X    = (const float*)d_in[0];   // [8192, 4096]
    const float* W    = (const float*)d_in[1];   // [512, 4096]
    const float* bias = (const float*)d_in[2];   // [512]
    float* out = (float*)d_out;

    const size_t wp_bytes = (size_t)NEXP * HID * 4;   // 8 MB (2 fp16 planes)

    if (ws_size >= wp_bytes) {
        uint4* Wp = (uint4*)d_ws;
        wconv_kernel<<<dim3(2048), dim3(256), 0, stream>>>(W, Wp);
        fused_kernel<<<dim3(T_TOKENS / 32), dim3(512), 0, stream>>>(X, Wp, bias, out);
    } else {
        router_kernel<<<dim3(T_TOKENS / TM), dim3(256), 0, stream>>>(X, W, bias, out);
    }
}